// Round 1
// baseline (244.842 us; speedup 1.0000x reference)
//
#include <hip/hip_runtime.h>
#include <hip/hip_bf16.h>
#include <math.h>

#define TAU_F       0.1f
#define EPS_NORM_F  1e-12f
#define EPS_DENOM_F 1e-8f

__device__ __forceinline__ float dot4(float4 a, float4 b) {
    return a.x * b.x + a.y * b.y + a.z * b.z + a.w * b.w;
}

// -----------------------------------------------------------------------------
// Kernel 1: per-row dot(row, anchor) and ||row||, for hard_negatives + positives.
// One wave (64 lanes) per row; lane i reads float4 i and i+64 of the 128-float4
// row (two fully coalesced 1KB wave transactions). Butterfly reduce.
// Stores cos to ws; accumulates sum(exp(cos/TAU)) over h-rows via f64 atomic.
// -----------------------------------------------------------------------------
__global__ void __launch_bounds__(256) rows_kernel(
        const float* __restrict__ anchor,
        const float* __restrict__ pos,
        const float* __restrict__ hn,
        float* __restrict__ cos_h,
        float* __restrict__ cos_p,
        double* __restrict__ S_acc,
        int n_hard, int n_pos) {
    const int lane = threadIdx.x & 63;
    const int wib  = threadIdx.x >> 6;             // wave index in block
    const int wpb  = blockDim.x >> 6;              // waves per block
    const int wid  = blockIdx.x * wpb + wib;       // global wave id
    const int nw   = gridDim.x * wpb;              // total waves

    // Anchor slice for this lane (whole anchor is covered by the 64 lanes).
    const float4* a4 = (const float4*)anchor;
    const float4 a0 = a4[lane];
    const float4 a1 = a4[lane + 64];

    // Anchor norm via the same wave reduction (slices tile all 512 elements).
    float na2 = dot4(a0, a0) + dot4(a1, a1);
    #pragma unroll
    for (int o = 32; o > 0; o >>= 1) na2 += __shfl_xor(na2, o, 64);
    const float na = fmaxf(sqrtf(na2), EPS_NORM_F);

    const int total = n_hard + n_pos;
    float local_exp = 0.0f;   // uniform across lanes after each reduce

    for (int r = wid; r < total; r += nw) {
        const bool is_h = (r < n_hard);
        const float4* row = is_h ? (const float4*)hn + (size_t)r * 128
                                 : (const float4*)pos + (size_t)(r - n_hard) * 128;
        const float4 v0 = row[lane];
        const float4 v1 = row[lane + 64];
        float s  = dot4(v0, a0) + dot4(v1, a1);
        float n2 = dot4(v0, v0) + dot4(v1, v1);
        #pragma unroll
        for (int o = 32; o > 0; o >>= 1) {
            s  += __shfl_xor(s,  o, 64);
            n2 += __shfl_xor(n2, o, 64);
        }
        const float nrm  = fmaxf(sqrtf(n2), EPS_NORM_F);
        const float cosv = s / (nrm * na);
        if (is_h) {
            if (lane == 0) cos_h[r] = cosv;
            local_exp += __expf(cosv / TAU_F) * 0.0f + expf(cosv / TAU_F); // use precise expf
        } else {
            if (lane == 0) cos_p[r - n_hard] = cosv;
        }
    }

    // Block-level reduce of the (lane-uniform) wave partial sums, then 1 atomic.
    __shared__ float sred[16];
    if (lane == 0) sred[wib] = local_exp;
    __syncthreads();
    if (threadIdx.x == 0) {
        float t = 0.0f;
        for (int i = 0; i < wpb; ++i) t += sred[i];
        atomicAdd(S_acc, (double)t);
    }
}

// -----------------------------------------------------------------------------
// Kernel 2: 2*n_mix synthetic negatives. One wave per item.
//   j <  n_mix : "hardest" — pure scalar math from cached cos_h value.
//   j >= n_mix : "harder"  — needs dot(h[a],h[b]) + both norms (wave pair-dot).
// Uses unit-norm algebra: h_norm and a_norm are unit vectors, so
//   dot(mix, a_norm) and ||mix|| collapse to scalar expressions.
// -----------------------------------------------------------------------------
__global__ void __launch_bounds__(256) mix_kernel(
        const float* __restrict__ hn,
        const float* __restrict__ cos_h,
        const int* __restrict__ mix_idx,
        const int* __restrict__ idx_a,
        const int* __restrict__ idx_b,
        const float* __restrict__ alpha_raw,
        const float* __restrict__ beta_raw,
        double* __restrict__ S_acc,
        int n_mix) {
    const int lane = threadIdx.x & 63;
    const int wib  = threadIdx.x >> 6;
    const int wpb  = blockDim.x >> 6;
    const int j    = blockIdx.x * wpb + wib;

    float e = 0.0f;   // lane-0 exp contribution of this wave's item

    if (j < n_mix) {
        if (lane == 0) {
            const float c  = cos_h[mix_idx[j]];
            const float al = alpha_raw[j] * 0.4f + 0.1f;
            const float num  = (1.0f - al) * c + al;
            const float den2 = (1.0f - al) * (1.0f - al) + al * al
                             + 2.0f * al * (1.0f - al) * c;
            const float cosm = num / fmaxf(sqrtf(den2), EPS_NORM_F);
            e = expf(cosm / TAU_F);
        }
    } else if (j < 2 * n_mix) {
        const int k  = j - n_mix;
        const int ra = idx_a[k];
        const int rb = idx_b[k];
        const float4* A = (const float4*)hn + (size_t)ra * 128;
        const float4* B = (const float4*)hn + (size_t)rb * 128;
        const float4 x0 = A[lane], x1 = A[lane + 64];
        const float4 y0 = B[lane], y1 = B[lane + 64];
        float d   = dot4(x0, y0) + dot4(x1, y1);
        float na2 = dot4(x0, x0) + dot4(x1, x1);
        float nb2 = dot4(y0, y0) + dot4(y1, y1);
        #pragma unroll
        for (int o = 32; o > 0; o >>= 1) {
            d   += __shfl_xor(d,   o, 64);
            na2 += __shfl_xor(na2, o, 64);
            nb2 += __shfl_xor(nb2, o, 64);
        }
        if (lane == 0) {
            const float na  = fmaxf(sqrtf(na2), EPS_NORM_F);
            const float nb  = fmaxf(sqrtf(nb2), EPS_NORM_F);
            const float dab = d / (na * nb);
            const float be  = beta_raw[k] * 0.4f + 0.3f;
            const float ca  = cos_h[ra];
            const float cb  = cos_h[rb];
            const float num  = be * ca + (1.0f - be) * cb;
            const float den2 = be * be + (1.0f - be) * (1.0f - be)
                             + 2.0f * be * (1.0f - be) * dab;
            const float cosm = num / fmaxf(sqrtf(den2), EPS_NORM_F);
            e = expf(cosm / TAU_F);
        }
    }

    __shared__ float sred[16];
    if (lane == 0) sred[wib] = e;
    __syncthreads();
    if (threadIdx.x == 0) {
        float t = 0.0f;
        for (int i = 0; i < wpb; ++i) t += sred[i];
        atomicAdd(S_acc, (double)t);
    }
}

// -----------------------------------------------------------------------------
// Kernel 3: final loss = mean_i [ -log(pv_i / (pv_i + S + 1e-8)) ].
// -----------------------------------------------------------------------------
__global__ void __launch_bounds__(256) loss_kernel(
        const float* __restrict__ cos_p,
        const double* __restrict__ S_acc,
        float* __restrict__ out,
        int n_pos) {
    __shared__ double sred[256];
    const float S = (float)S_acc[0];
    double acc = 0.0;
    for (int i = threadIdx.x; i < n_pos; i += blockDim.x) {
        const float l  = cos_p[i] / TAU_F;
        const float pv = expf(l);
        acc += (double)(-logf(pv / (pv + S + EPS_DENOM_F)));
    }
    sred[threadIdx.x] = acc;
    __syncthreads();
    for (int s = blockDim.x >> 1; s > 0; s >>= 1) {
        if (threadIdx.x < (unsigned)s) sred[threadIdx.x] += sred[threadIdx.x + s];
        __syncthreads();
    }
    if (threadIdx.x == 0) out[0] = (float)(sred[0] / (double)n_pos);
}

extern "C" void kernel_launch(void* const* d_in, const int* in_sizes, int n_in,
                              void* d_out, int out_size, void* d_ws, size_t ws_size,
                              hipStream_t stream) {
    const float* anchor    = (const float*)d_in[0];
    const float* positives = (const float*)d_in[1];
    const float* hardnegs  = (const float*)d_in[2];
    const int*   mix_idx   = (const int*)d_in[3];
    const int*   idx_a     = (const int*)d_in[4];
    const int*   idx_b     = (const int*)d_in[5];
    const float* alpha_raw = (const float*)d_in[6];
    const float* beta_raw  = (const float*)d_in[7];

    const int D      = in_sizes[0];          // 512
    const int n_pos  = in_sizes[1] / D;      // 8192
    const int n_hard = in_sizes[2] / D;      // 65536
    const int n_mix  = in_sizes[3];          // 64

    // Workspace layout: [0..8) f64 accumulator | [16..) cos_h | cos_p
    char*   ws    = (char*)d_ws;
    double* S_acc = (double*)ws;
    float*  cos_h = (float*)(ws + 16);
    float*  cos_p = cos_h + n_hard;

    hipMemsetAsync(S_acc, 0, sizeof(double), stream);

    // Main pass: 2048 blocks x 4 waves = 8192 waves grid-striding 73728 rows.
    rows_kernel<<<2048, 256, 0, stream>>>(anchor, positives, hardnegs,
                                          cos_h, cos_p, S_acc, n_hard, n_pos);

    // Synthetic negatives: 2*n_mix waves.
    const int mix_waves  = 2 * n_mix;
    const int mix_blocks = (mix_waves + 3) / 4;
    mix_kernel<<<mix_blocks, 256, 0, stream>>>(hardnegs, cos_h, mix_idx, idx_a,
                                               idx_b, alpha_raw, beta_raw,
                                               S_acc, n_mix);

    // Final reduction over positives.
    loss_kernel<<<1, 256, 0, stream>>>(cos_p, S_acc, (float*)d_out, n_pos);
}